// Round 8
// baseline (1737.682 us; speedup 1.0000x reference)
//
#include <hip/hip_runtime.h>
#include <hip/hip_bf16.h>

#define N_NODES 100000
#define N_EDGES 1600000
#define IN_CH 50
#define NPB 128                                   // nodes per bucket (dst >> 7)
#define NB ((N_NODES + NPB - 1) / NPB)            // 782 buckets
#define EPB 4096                                  // edges per block, binning passes
#define NBLK_A ((N_EDGES + EPB - 1) / EPB)        // 391 blocks

// ---- 1. coarse bucket histogram (bins = dst>>7) ----
__global__ __launch_bounds__(256) void bucket_count(const int* __restrict__ dst,
                                                    int* __restrict__ bucket_cnt) {
    __shared__ int bc[NB];
    int t = threadIdx.x;
    for (int b = t; b < NB; b += 256) bc[b] = 0;
    __syncthreads();
    int e0 = blockIdx.x * EPB;
    int e1 = min(e0 + EPB, N_EDGES);
    for (int i = e0 + t; i < e1; i += 256)
        atomicAdd(&bc[dst[i] >> 7], 1);
    __syncthreads();
    for (int b = t; b < NB; b += 256) {
        int v = bc[b]; if (v) atomicAdd(&bucket_cnt[b], v);
    }
}

// ---- 2. exclusive scan of bucket sizes (1024 threads, NB<=1024) ----
__global__ __launch_bounds__(1024) void bucket_scan(const int* __restrict__ bucket_cnt,
                                                    int* __restrict__ bucket_base,
                                                    int* __restrict__ bucket_cursor) {
    __shared__ int s[1024];
    int t = threadIdx.x;
    int v = (t < NB) ? bucket_cnt[t] : 0;
    s[t] = v;
    __syncthreads();
    for (int off = 1; off < 1024; off <<= 1) {
        int tmp = (t >= off) ? s[t - off] : 0;
        __syncthreads();
        s[t] += tmp;
        __syncthreads();
    }
    if (t < NB) { int base = s[t] - v; bucket_base[t] = base; bucket_cursor[t] = base; }
}

// ---- 3. bin edges into buckets as packed u32: (dst&127)<<17 | src ----
__global__ __launch_bounds__(256) void bucket_bin(const int* __restrict__ src,
                                                  const int* __restrict__ dst,
                                                  int* __restrict__ bucket_cursor,
                                                  unsigned* __restrict__ binned) {
    __shared__ int bc[NB];
    __shared__ int boff[NB];
    int t = threadIdx.x;
    for (int b = t; b < NB; b += 256) bc[b] = 0;
    __syncthreads();
    int e0 = blockIdx.x * EPB;
    int e1 = min(e0 + EPB, N_EDGES);
    for (int i = e0 + t; i < e1; i += 256)
        atomicAdd(&bc[dst[i] >> 7], 1);
    __syncthreads();
    for (int b = t; b < NB; b += 256) {
        int v = bc[b];
        boff[b] = v ? atomicAdd(&bucket_cursor[b], v) : 0;
        bc[b] = 0;                                 // reuse as local cursor
    }
    __syncthreads();
    for (int i = e0 + t; i < e1; i += 256) {
        int d = dst[i];
        int b = d >> 7;
        int k = atomicAdd(&bc[b], 1);
        binned[boff[b] + k] = ((unsigned)(d & 127) << 17) | (unsigned)src[i];
    }
}

// ---- 4. pre1: pad x->xb (bf16) + dense self GEMM pre = x @ W1[0:50] + b1 ----
__global__ __launch_bounds__(256) void pre1_kernel(const float* __restrict__ x,
                                                   const float* __restrict__ W1,
                                                   const float* __restrict__ b1,
                                                   unsigned short* __restrict__ xb,
                                                   float* __restrict__ pre) {
    __shared__ float xs[64 * IN_CH];               // 12.8 KB
    int t = threadIdx.x;
    int nbase = blockIdx.x * 64;
    int lim = (min(64, N_NODES - nbase)) * IN_CH;
    for (int i = t; i < 64 * IN_CH; i += 256)
        xs[i] = (i < lim) ? x[nbase * IN_CH + i] : 0.0f;
    __syncthreads();
    for (int i = t; i < 64 * 64; i += 256) {
        int n = i >> 6, c = i & 63;
        if (nbase + n < N_NODES) {
            float v = (c < IN_CH) ? xs[n * IN_CH + c] : 0.0f;
            __hip_bfloat16 hb = __float2bfloat16(v);
            xb[((nbase + n) << 6) + c] = *(unsigned short*)&hb;
        }
    }
    int wv = t >> 6, lane = t & 63;
    float bb = b1[lane];
    for (int gq = 0; gq < 4; ++gq) {
        int n0 = wv * 16 + gq * 4;
        float ao[4] = {bb, bb, bb, bb};
        for (int k = 0; k < IN_CH; ++k) {
            float w = W1[k * 64 + lane];
            #pragma unroll
            for (int i = 0; i < 4; ++i) ao[i] = fmaf(xs[(n0 + i) * IN_CH + k], w, ao[i]);
        }
        #pragma unroll
        for (int i = 0; i < 4; ++i) {
            int gn = nbase + n0 + i;
            if (gn < N_NODES) pre[(gn << 6) + lane] = ao[i];
        }
    }
}

// ---- 5. pre2: dense self GEMM pre2 = h1b @ W2[0:64] + b2 ----
__global__ __launch_bounds__(256) void pre2_kernel(const unsigned short* __restrict__ h1b,
                                                   const float* __restrict__ W2,
                                                   const float* __restrict__ b2,
                                                   float* __restrict__ pre2) {
    __shared__ float hs[64 * 64];                  // 16 KB
    int t = threadIdx.x;
    int nbase = blockIdx.x * 64;
    const unsigned* h32 = (const unsigned*)h1b;    // 2 ch per uint
    int lim32 = (min(64, N_NODES - nbase)) * 32;
    for (int i = t; i < 64 * 32; i += 256) {
        unsigned u = (i < lim32) ? h32[nbase * 32 + i] : 0u;
        hs[2 * i]     = __uint_as_float(u << 16);
        hs[2 * i + 1] = __uint_as_float(u & 0xffff0000u);
    }
    __syncthreads();
    int hw = t >> 5, j = t & 31;                   // 8 half-waves x 8 nodes
    float bb = b2[j];
    for (int gq = 0; gq < 2; ++gq) {
        int n0 = hw * 8 + gq * 4;
        float ao[4] = {bb, bb, bb, bb};
        for (int k = 0; k < 64; ++k) {
            float w = W2[k * 32 + j];
            #pragma unroll
            for (int i = 0; i < 4; ++i) ao[i] = fmaf(hs[((n0 + i) << 6) + k], w, ao[i]);
        }
        #pragma unroll
        for (int i = 0; i < 4; ++i) {
            int gn = nbase + n0 + i;
            if (gn < N_NODES) pre2[gn * 32 + j] = ao[i];
        }
    }
}

// ---- edge-parallel scatter round: 8 edges, lanes (g=lane>>3, q=lane&7) ----
// bf16 row 64ch: lane loads 16B (8 ch) of edge g's src row, ds_add into acc.
__device__ __forceinline__ void scatter_round(
    const unsigned* __restrict__ binned, const unsigned short* __restrict__ featb,
    float* __restrict__ acc, int* __restrict__ lcnt,
    int i0, int eend, int g, int q, bool pred) {
    int ei = i0 + g;
    unsigned e = binned[ei];                       // bounded over-read: lands in next ws region
    float p = pred ? ((ei < eend) ? 1.0f : 0.0f) : 1.0f;
    int s = min((int)(e & 0x1FFFFu), N_NODES - 1); // clamp garbage src
    int d = (int)(e >> 17) & 127;
    uint4 v = *(const uint4*)(featb + s * 64 + q * 8);
    float* ap = acc + d * 65 + q * 8;              // stride 65: banks ~ (d + 8(q&3) + j)
    atomicAdd(&ap[0], p * __uint_as_float(v.x << 16));
    atomicAdd(&ap[1], p * __uint_as_float(v.x & 0xffff0000u));
    atomicAdd(&ap[2], p * __uint_as_float(v.y << 16));
    atomicAdd(&ap[3], p * __uint_as_float(v.y & 0xffff0000u));
    atomicAdd(&ap[4], p * __uint_as_float(v.z << 16));
    atomicAdd(&ap[5], p * __uint_as_float(v.z & 0xffff0000u));
    atomicAdd(&ap[6], p * __uint_as_float(v.w << 16));
    atomicAdd(&ap[7], p * __uint_as_float(v.w & 0xffff0000u));
    if (q == 0) atomicAdd(&lcnt[d], (int)p);
}

// ---- 6. mega1: per-bucket LDS aggregate(xb) + mean GEMM + relu -> h1b ----
__global__ __launch_bounds__(256) void mega1_kernel(
    const unsigned* __restrict__ binned, const int* __restrict__ bucket_base,
    const int* __restrict__ bucket_cnt, const unsigned short* __restrict__ xb,
    const float* __restrict__ W1, const float* __restrict__ pre,
    unsigned short* __restrict__ h1b) {
    __shared__ float acc[NPB * 65];                // 33.3 KB
    __shared__ int lcnt[NPB];
    int t = threadIdx.x;
    for (int i = t; i < NPB * 65; i += 256) acc[i] = 0.0f;
    if (t < NPB) lcnt[t] = 0;
    __syncthreads();
    int b = blockIdx.x;
    int ebase = bucket_base[b];
    int eend  = ebase + bucket_cnt[b];
    int wv = t >> 6, lane = t & 63;
    int g = lane >> 3, q = lane & 7;
    int i0 = ebase + wv * 8;
    for (; i0 + 32 < eend; i0 += 64) {
        scatter_round(binned, xb, acc, lcnt, i0, eend, g, q, false);
        scatter_round(binned, xb, acc, lcnt, i0 + 32, eend, g, q, true);
    }
    if (i0 < eend)
        scatter_round(binned, xb, acc, lcnt, i0, eend, g, q, true);
    __syncthreads();
    // mean GEMM: t_i = sum_k acc[n][k] * W1[(50+k)*64+j]; h = relu(pre + t*inv)
    int nbase = b * NPB;
    for (int gq = 0; gq < 8; ++gq) {               // wave: 32 nodes = 8 groups of 4
        int n0 = wv * 32 + gq * 4;
        float ta[4] = {0.f, 0.f, 0.f, 0.f};
        for (int k = 0; k < IN_CH; ++k) {
            float w = W1[(IN_CH + k) * 64 + lane];
            #pragma unroll
            for (int i = 0; i < 4; ++i) ta[i] = fmaf(acc[(n0 + i) * 65 + k], w, ta[i]);
        }
        #pragma unroll
        for (int i = 0; i < 4; ++i) {
            int gn = nbase + n0 + i;
            if (gn < N_NODES) {
                float inv = 1.0f / fmaxf((float)lcnt[n0 + i], 1.0f);
                float r = fmaxf(pre[(gn << 6) + lane] + ta[i] * inv, 0.0f);
                __hip_bfloat16 hb = __float2bfloat16(r);
                h1b[(gn << 6) + lane] = *(unsigned short*)&hb;
            }
        }
    }
}

// ---- 7. mega2: per-bucket LDS aggregate(h1b) + mean GEMM + relu + W3 dot -> out ----
__global__ __launch_bounds__(256) void mega2_kernel(
    const unsigned* __restrict__ binned, const int* __restrict__ bucket_base,
    const int* __restrict__ bucket_cnt, const unsigned short* __restrict__ h1b,
    const float* __restrict__ W2, const float* __restrict__ pre2,
    const float* __restrict__ W3, const float* __restrict__ b3,
    float* __restrict__ out) {
    __shared__ float acc[NPB * 65];
    __shared__ int lcnt[NPB];
    int t = threadIdx.x;
    for (int i = t; i < NPB * 65; i += 256) acc[i] = 0.0f;
    if (t < NPB) lcnt[t] = 0;
    __syncthreads();
    int b = blockIdx.x;
    int ebase = bucket_base[b];
    int eend  = ebase + bucket_cnt[b];
    int wv = t >> 6, lane = t & 63;
    int g = lane >> 3, q = lane & 7;
    int i0 = ebase + wv * 8;
    for (; i0 + 32 < eend; i0 += 64) {
        scatter_round(binned, h1b, acc, lcnt, i0, eend, g, q, false);
        scatter_round(binned, h1b, acc, lcnt, i0 + 32, eend, g, q, true);
    }
    if (i0 < eend)
        scatter_round(binned, h1b, acc, lcnt, i0, eend, g, q, true);
    __syncthreads();
    int nbase = b * NPB;
    int hh = lane >> 5;                            // half-wave id
    int j  = lane & 31;
    float w3 = W3[j];
    float c3 = b3[0];
    for (int gq = 0; gq < 4; ++gq) {               // wave: 32 nodes (16 per half)
        int n0 = wv * 32 + hh * 16 + gq * 4;
        float ta[4] = {0.f, 0.f, 0.f, 0.f};
        for (int k = 0; k < 64; ++k) {
            float w = W2[(64 + k) * 32 + j];
            #pragma unroll
            for (int i = 0; i < 4; ++i) ta[i] = fmaf(acc[(n0 + i) * 65 + k], w, ta[i]);
        }
        #pragma unroll
        for (int i = 0; i < 4; ++i) {
            int gn = nbase + n0 + i;
            float inv = 1.0f / fmaxf((float)lcnt[n0 + i], 1.0f);
            float pv = (gn < N_NODES) ? pre2[gn * 32 + j] : 0.0f;
            float v = fmaxf(pv + ta[i] * inv, 0.0f) * w3;
            v += __shfl_xor(v, 1);  v += __shfl_xor(v, 2);  v += __shfl_xor(v, 4);
            v += __shfl_xor(v, 8);  v += __shfl_xor(v, 16);
            if (j == 0 && gn < N_NODES) out[gn] = v + c3;
        }
    }
}

extern "C" void kernel_launch(void* const* d_in, const int* in_sizes, int n_in,
                              void* d_out, int out_size, void* d_ws, size_t ws_size,
                              hipStream_t stream) {
    const float* x   = (const float*)d_in[0];
    const int*   ei  = (const int*)d_in[1];
    const int*   src = ei;
    const int*   dst = ei + N_EDGES;
    const float* W1  = (const float*)d_in[2];
    const float* b1  = (const float*)d_in[3];
    const float* W2  = (const float*)d_in[4];
    const float* b2  = (const float*)d_in[5];
    const float* W3  = (const float*)d_in[6];
    const float* b3  = (const float*)d_in[7];
    float* out = (float*)d_out;

    // ws (~58 MB): bucket arrays | binned u32[E] 6.4MB | xb bf16 12.8MB |
    //   h1b bf16 12.8MB | pre f32[N*64] 25.6MB (pre2 f32[N*32] ALIASES pre:
    //   pre dead after mega1, pre2 written after)
    char* ws = (char*)d_ws;
    auto align = [](size_t v) { return (v + 255) & ~(size_t)255; };
    size_t o = 0;
    int* bucket_cnt    = (int*)(ws + o); o = align(o + (size_t)NB * 4);
    int* bucket_base   = (int*)(ws + o); o = align(o + (size_t)NB * 4);
    int* bucket_cursor = (int*)(ws + o); o = align(o + (size_t)NB * 4);
    unsigned* binned   = (unsigned*)(ws + o); o = align(o + (size_t)N_EDGES * 4);
    unsigned short* xb  = (unsigned short*)(ws + o); o = align(o + (size_t)N_NODES * 64 * 2);
    unsigned short* h1b = (unsigned short*)(ws + o); o = align(o + (size_t)N_NODES * 64 * 2);
    float* pre  = (float*)(ws + o);
    float* pre2 = (float*)(ws + o);                // alias, sequential lifetimes
    o = align(o + (size_t)N_NODES * 64 * 4);

    hipMemsetAsync(bucket_cnt, 0, (size_t)NB * sizeof(int), stream);

    bucket_count<<<NBLK_A, 256, 0, stream>>>(dst, bucket_cnt);
    bucket_scan<<<1, 1024, 0, stream>>>(bucket_cnt, bucket_base, bucket_cursor);
    bucket_bin<<<NBLK_A, 256, 0, stream>>>(src, dst, bucket_cursor, binned);
    pre1_kernel<<<(N_NODES + 63) / 64, 256, 0, stream>>>(x, W1, b1, xb, pre);

    mega1_kernel<<<NB, 256, 0, stream>>>(binned, bucket_base, bucket_cnt,
                                         xb, W1, pre, h1b);
    pre2_kernel<<<(N_NODES + 63) / 64, 256, 0, stream>>>(h1b, W2, b2, pre2);
    mega2_kernel<<<NB, 256, 0, stream>>>(binned, bucket_base, bucket_cnt,
                                         h1b, W2, pre2, W3, b3, out);
}

// Round 9
// 427.141 us; speedup vs baseline: 4.0682x; 4.0682x over previous
//
#include <hip/hip_runtime.h>
#include <hip/hip_bf16.h>

#define N_NODES 100000
#define N_EDGES 1600000
#define IN_CH 50
#define NPB 512                                   // nodes per bucket (dst >> 9)
#define NB ((N_NODES + NPB - 1) / NPB)            // 196 buckets
#define EPB 4096                                  // edges per block, binning passes
#define NBLK_A ((N_EDGES + EPB - 1) / EPB)        // 391 blocks
#define PAD_BLOCKS ((N_NODES * 64) / 256)         // 25000

// ---- 1. coarse bucket histogram + (extra blocks) pad x -> xb bf16 ----
__global__ __launch_bounds__(256) void count_pad_kernel(const int* __restrict__ dst,
                                                        int* __restrict__ bucket_cnt,
                                                        const float* __restrict__ x,
                                                        unsigned short* __restrict__ xb) {
    __shared__ int bc[NB];
    if (blockIdx.x < NBLK_A) {
        int t = threadIdx.x;
        if (t < NB) bc[t] = 0;
        __syncthreads();
        int e0 = blockIdx.x * EPB;
        int e1 = min(e0 + EPB, N_EDGES);
        for (int i = e0 + t; i < e1; i += 256)
            atomicAdd(&bc[dst[i] >> 9], 1);
        __syncthreads();
        if (t < NB) { int v = bc[t]; if (v) atomicAdd(&bucket_cnt[t], v); }
    } else {
        int t = (blockIdx.x - NBLK_A) * 256 + threadIdx.x;   // < N_NODES*64
        int n = t >> 6, c = t & 63;
        float v = (c < IN_CH) ? x[n * IN_CH + c] : 0.0f;
        __hip_bfloat16 hb = __float2bfloat16(v);
        xb[t] = *(unsigned short*)&hb;
    }
}

// ---- 2. exclusive scan of bucket sizes ----
__global__ __launch_bounds__(256) void bucket_scan(const int* __restrict__ bucket_cnt,
                                                   int* __restrict__ bucket_base,
                                                   int* __restrict__ bucket_cursor) {
    __shared__ int s[256];
    int t = threadIdx.x;
    int v = (t < NB) ? bucket_cnt[t] : 0;
    s[t] = v;
    __syncthreads();
    for (int off = 1; off < 256; off <<= 1) {
        int tmp = (t >= off) ? s[t - off] : 0;
        __syncthreads();
        s[t] += tmp;
        __syncthreads();
    }
    if (t < NB) { int base = s[t] - v; bucket_base[t] = base; bucket_cursor[t] = base; }
}

// ---- 3. bin edges as packed u32: (dst&511)<<17 | src  (src < 2^17) ----
__global__ __launch_bounds__(256) void bucket_bin(const int* __restrict__ src,
                                                  const int* __restrict__ dst,
                                                  int* __restrict__ bucket_cursor,
                                                  unsigned* __restrict__ binned) {
    __shared__ int bc[NB];
    __shared__ int boff[NB];
    int t = threadIdx.x;
    if (t < NB) bc[t] = 0;
    __syncthreads();
    int e0 = blockIdx.x * EPB;
    int e1 = min(e0 + EPB, N_EDGES);
    for (int i = e0 + t; i < e1; i += 256)
        atomicAdd(&bc[dst[i] >> 9], 1);
    __syncthreads();
    if (t < NB) {
        int v = bc[t];
        boff[t] = v ? atomicAdd(&bucket_cursor[t], v) : 0;
        bc[t] = 0;                                 // reuse as local cursor
    }
    __syncthreads();
    for (int i = e0 + t; i < e1; i += 256) {
        int d = dst[i];
        int b = d >> 9;
        int k = atomicAdd(&bc[b], 1);
        binned[boff[b] + k] = ((unsigned)(d & 511) << 17) | (unsigned)src[i];
    }
}

// ---- 4. per-bucket fine sort (u32 payload) ----
__global__ __launch_bounds__(256) void bucket_fine(
    const unsigned* __restrict__ binned,
    const int* __restrict__ bucket_base, const int* __restrict__ bucket_cnt,
    int* __restrict__ cnt, int* __restrict__ row_start, int* __restrict__ csr_src) {
    __shared__ int lcnt[NPB];
    __shared__ int lofs[NPB];
    __shared__ int sc[256];
    int t = threadIdx.x;
    int b = blockIdx.x;
    int nbase = b * NPB;
    int ebase = bucket_base[b];
    int ecnt  = bucket_cnt[b];
    lcnt[t] = 0; lcnt[t + 256] = 0;
    __syncthreads();
    for (int i = t; i < ecnt; i += 256)
        atomicAdd(&lcnt[(binned[ebase + i] >> 17) & 511], 1);
    __syncthreads();
    int v0 = lcnt[2 * t], v1 = lcnt[2 * t + 1];
    int pair = v0 + v1;
    sc[t] = pair;
    __syncthreads();
    for (int off = 1; off < 256; off <<= 1) {
        int tmp = (t >= off) ? sc[t - off] : 0;
        __syncthreads();
        sc[t] += tmp;
        __syncthreads();
    }
    int excl = sc[t] - pair;
    lofs[2 * t] = excl;
    lofs[2 * t + 1] = excl + v0;
    __syncthreads();
    {
        int n0 = nbase + t;
        if (n0 < N_NODES) { cnt[n0] = lcnt[t]; row_start[n0] = ebase + lofs[t]; }
        int n1 = nbase + t + 256;
        if (n1 < N_NODES) { cnt[n1] = lcnt[t + 256]; row_start[n1] = ebase + lofs[t + 256]; }
    }
    __syncthreads();
    for (int i = t; i < ecnt; i += 256) {
        unsigned p = binned[ebase + i];
        int d = (int)((p >> 17) & 511);
        int k = atomicAdd(&lofs[d], 1);
        csr_src[ebase + k] = (int)(p & 0x1FFFFu);
    }
}

// unpack 8 bf16 from uint4, predicated fma into acc[0..8)
__device__ __forceinline__ void upadd8(float* a, uint4 v, float p) {
    a[0] = fmaf(p, __uint_as_float(v.x << 16), a[0]);
    a[1] = fmaf(p, __uint_as_float(v.x & 0xffff0000u), a[1]);
    a[2] = fmaf(p, __uint_as_float(v.y << 16), a[2]);
    a[3] = fmaf(p, __uint_as_float(v.y & 0xffff0000u), a[3]);
    a[4] = fmaf(p, __uint_as_float(v.z << 16), a[4]);
    a[5] = fmaf(p, __uint_as_float(v.z & 0xffff0000u), a[5]);
    a[6] = fmaf(p, __uint_as_float(v.w << 16), a[6]);
    a[7] = fmaf(p, __uint_as_float(v.w & 0xffff0000u), a[7]);
}

// wave-local LDS fence: LDS ops of one wave complete in order; no block barrier.
#define WAVE_LDS_FENCE() __asm__ volatile("s_waitcnt lgkmcnt(0)" ::: "memory")

// Gather-mean of 8 nodes (nb..nb+7) per wave, chains interleaved.
// 8 lane-groups of 8; each lane loads 16B (8 bf16 ch) of one edge row.
// On return: acc[i][c] = mean (divided), all lanes, channels (lane&7)*8+c.
__device__ __forceinline__ void gather8(
    const unsigned short* __restrict__ featb, const int* __restrict__ csr_src,
    const int* __restrict__ row_start, const int* __restrict__ cnt,
    int nb, int lane, float acc[8][8]) {
    int g  = lane >> 3;
    int cw = (lane & 7) * 8;
    int start[8], deg[8], sv[8];
    int dmax = 0;
    #pragma unroll
    for (int i = 0; i < 8; ++i) {
        start[i] = row_start[nb + i];
        deg[i]   = cnt[nb + i];
        dmax = max(dmax, deg[i]);
        #pragma unroll
        for (int c = 0; c < 8; ++c) acc[i][c] = 0.f;
    }
    #pragma unroll
    for (int i = 0; i < 8; ++i)
        sv[i] = (lane < deg[i]) ? csr_src[start[i] + lane] : 0;

    #pragma unroll
    for (int cb = 0; cb < 64; cb += 16) {
        if (cb >= dmax) break;                 // wave-uniform
        #pragma unroll
        for (int i = 0; i < 8; ++i) {
            int rem = deg[i] - cb;
            if (rem > 0) {                     // wave-uniform
                int s0 = __shfl(sv[i], cb + g);
                int s1 = __shfl(sv[i], cb + 8 + g);
                float p0 = (g < rem) ? 1.f : 0.f;
                float p1 = (g + 8 < rem) ? 1.f : 0.f;
                uint4 v0 = *(const uint4*)(featb + s0 * 64 + cw);
                uint4 v1 = *(const uint4*)(featb + s1 * 64 + cw);
                upadd8(acc[i], v0, p0);
                upadd8(acc[i], v1, p1);
            }
        }
    }
    if (dmax > 64) {                           // rare tail
        for (int i = 0; i < 8; ++i) {
            for (int c0 = 64; c0 < deg[i]; c0 += 64) {
                int rem = deg[i] - c0; if (rem > 64) rem = 64;
                int sx = (lane < rem) ? csr_src[start[i] + c0 + lane] : 0;
                for (int cb = 0; cb < rem; cb += 16) {
                    int s0 = __shfl(sx, cb + g);
                    int s1 = __shfl(sx, cb + 8 + g);
                    float p0 = (cb + g < rem) ? 1.f : 0.f;
                    float p1 = (cb + 8 + g < rem) ? 1.f : 0.f;
                    uint4 v0 = *(const uint4*)(featb + s0 * 64 + cw);
                    uint4 v1 = *(const uint4*)(featb + s1 * 64 + cw);
                    upadd8(acc[i], v0, p0);
                    upadd8(acc[i], v1, p1);
                }
            }
        }
    }
    #pragma unroll
    for (int i = 0; i < 8; ++i) {
        float inv = 1.0f / fmaxf((float)deg[i], 1.0f);
        #pragma unroll
        for (int c = 0; c < 8; ++c) {
            float t = acc[i][c];
            t += __shfl_xor(t, 8);
            t += __shfl_xor(t, 16);
            t += __shfl_xor(t, 32);
            acc[i][c] = t * inv;
        }
    }
}

// ---- 5. layer 1 fused: 8 nodes/wave; gather(xb) + GEMM(100x64) + ReLU ----
__global__ __launch_bounds__(256) void layer1_fused(
    const float* __restrict__ x, const unsigned short* __restrict__ xb,
    const int* __restrict__ csr_src, const int* __restrict__ row_start,
    const int* __restrict__ cnt, const float* __restrict__ W1,
    const float* __restrict__ b1, float* __restrict__ h1,
    unsigned short* __restrict__ h1b) {
    int wv   = threadIdx.x >> 6;
    int lane = threadIdx.x & 63;
    int nb   = (blockIdx.x * 4 + wv) * 8;      // 100000 % 32 == 0

    float acc[8][8];
    gather8(xb, csr_src, row_start, cnt, nb, lane, acc);

    __shared__ __align__(16) float selfF[4][8][64];
    __shared__ __align__(16) float meanF[4][8][64];
    #pragma unroll
    for (int i = 0; i < 8; ++i) {
        if (lane < IN_CH) selfF[wv][i][lane] = x[(nb + i) * IN_CH + lane];
        if (lane < 8) {
            *(float4*)&meanF[wv][i][lane * 8] =
                make_float4(acc[i][0], acc[i][1], acc[i][2], acc[i][3]);
            *(float4*)&meanF[wv][i][lane * 8 + 4] =
                make_float4(acc[i][4], acc[i][5], acc[i][6], acc[i][7]);
        }
    }
    WAVE_LDS_FENCE();

    float ao[8];
    float bb = b1[lane];
    #pragma unroll
    for (int i = 0; i < 8; ++i) ao[i] = bb;
    #pragma unroll
    for (int k = 0; k < IN_CH; ++k) {
        float w = W1[k * 64 + lane];           // loaded once, reused x8
        #pragma unroll
        for (int i = 0; i < 8; ++i) ao[i] = fmaf(selfF[wv][i][k], w, ao[i]);
    }
    #pragma unroll
    for (int k = 0; k < IN_CH; ++k) {
        float w = W1[(IN_CH + k) * 64 + lane];
        #pragma unroll
        for (int i = 0; i < 8; ++i) ao[i] = fmaf(meanF[wv][i][k], w, ao[i]);
    }
    #pragma unroll
    for (int i = 0; i < 8; ++i) {
        float r = fmaxf(ao[i], 0.f);
        h1[((nb + i) << 6) + lane] = r;
        __hip_bfloat16 hb = __float2bfloat16(r);
        h1b[((nb + i) << 6) + lane] = *(unsigned short*)&hb;
    }
}

// ---- 6. layers 2+3 fused: 8 nodes/wave; gather(h1b) + GEMM(128x32) + ReLU + dot(W3) ----
__global__ __launch_bounds__(256) void layer23_fused(
    const float* __restrict__ h1, const unsigned short* __restrict__ h1b,
    const int* __restrict__ csr_src, const int* __restrict__ row_start,
    const int* __restrict__ cnt, const float* __restrict__ W2,
    const float* __restrict__ b2, const float* __restrict__ W3,
    const float* __restrict__ b3, float* __restrict__ out) {
    int wv   = threadIdx.x >> 6;
    int lane = threadIdx.x & 63;
    int nb   = (blockIdx.x * 4 + wv) * 8;

    float acc[8][8];
    gather8(h1b, csr_src, row_start, cnt, nb, lane, acc);

    __shared__ __align__(16) float featL[4][8][128];   // [0,64)=self, [64,128)=mean
    #pragma unroll
    for (int i = 0; i < 8; ++i) {
        featL[wv][i][lane] = h1[((nb + i) << 6) + lane];
        if (lane < 8) {
            *(float4*)&featL[wv][i][64 + lane * 8] =
                make_float4(acc[i][0], acc[i][1], acc[i][2], acc[i][3]);
            *(float4*)&featL[wv][i][64 + lane * 8 + 4] =
                make_float4(acc[i][4], acc[i][5], acc[i][6], acc[i][7]);
        }
    }
    WAVE_LDS_FENCE();

    int hh = lane >> 5;                        // half-wave: nodes hh*4 .. hh*4+3
    int j  = lane & 31;
    int n0 = hh * 4;
    float a[4];
    float bb = b2[j];
    #pragma unroll
    for (int i = 0; i < 4; ++i) a[i] = bb;
    #pragma unroll
    for (int k = 0; k < 128; ++k) {
        float w = W2[k * 32 + j];              // loaded once, reused x4
        #pragma unroll
        for (int i = 0; i < 4; ++i) a[i] = fmaf(featL[wv][n0 + i][k], w, a[i]);
    }
    float w3 = W3[j];
    float c3 = b3[0];
    #pragma unroll
    for (int i = 0; i < 4; ++i) {
        float v = fmaxf(a[i], 0.f) * w3;
        v += __shfl_xor(v, 1);  v += __shfl_xor(v, 2);  v += __shfl_xor(v, 4);
        v += __shfl_xor(v, 8);  v += __shfl_xor(v, 16);
        if (j == 0) out[nb + n0 + i] = v + c3;
    }
}

extern "C" void kernel_launch(void* const* d_in, const int* in_sizes, int n_in,
                              void* d_out, int out_size, void* d_ws, size_t ws_size,
                              hipStream_t stream) {
    const float* x   = (const float*)d_in[0];
    const int*   ei  = (const int*)d_in[1];
    const int*   src = ei;
    const int*   dst = ei + N_EDGES;
    const float* W1  = (const float*)d_in[2];
    const float* b1  = (const float*)d_in[3];
    const float* W2  = (const float*)d_in[4];
    const float* b2  = (const float*)d_in[5];
    const float* W3  = (const float*)d_in[6];
    const float* b3  = (const float*)d_in[7];
    float* out = (float*)d_out;

    // ws (~52 MB): buckets | cnt | row_start | csr_src |
    //   binned u32[E] 6.4MB | xb bf16 12.8MB | h1b bf16 12.8MB | h1 f32 25.6MB
    char* ws = (char*)d_ws;
    auto align = [](size_t v) { return (v + 255) & ~(size_t)255; };
    size_t o = 0;
    int* bucket_cnt    = (int*)(ws + o); o = align(o + 256 * 4);
    int* bucket_base   = (int*)(ws + o); o = align(o + 256 * 4);
    int* bucket_cursor = (int*)(ws + o); o = align(o + 256 * 4);
    int* cnt       = (int*)(ws + o); o = align(o + (size_t)N_NODES * 4);
    int* row_start = (int*)(ws + o); o = align(o + (size_t)N_NODES * 4);
    int* csr_src   = (int*)(ws + o); o = align(o + (size_t)N_EDGES * 4);
    unsigned* binned = (unsigned*)(ws + o); o = align(o + (size_t)N_EDGES * 4);
    unsigned short* xb  = (unsigned short*)(ws + o); o = align(o + (size_t)N_NODES * 64 * 2);
    unsigned short* h1b = (unsigned short*)(ws + o); o = align(o + (size_t)N_NODES * 64 * 2);
    float* h1 = (float*)(ws + o); o = align(o + (size_t)N_NODES * 64 * 4);

    hipMemsetAsync(bucket_cnt, 0, 256 * sizeof(int), stream);

    count_pad_kernel<<<NBLK_A + PAD_BLOCKS, 256, 0, stream>>>(dst, bucket_cnt, x, xb);
    bucket_scan<<<1, 256, 0, stream>>>(bucket_cnt, bucket_base, bucket_cursor);
    bucket_bin<<<NBLK_A, 256, 0, stream>>>(src, dst, bucket_cursor, binned);
    bucket_fine<<<NB, 256, 0, stream>>>(binned, bucket_base, bucket_cnt,
                                        cnt, row_start, csr_src);

    layer1_fused<<<N_NODES / 32, 256, 0, stream>>>(x, xb, csr_src, row_start, cnt,
                                                   W1, b1, h1, h1b);
    layer23_fused<<<N_NODES / 32, 256, 0, stream>>>(h1, h1b, csr_src, row_start, cnt,
                                                    W2, b2, W3, b3, out);
}

// Round 10
// 281.003 us; speedup vs baseline: 6.1839x; 1.5201x over previous
//
#include <hip/hip_runtime.h>
#include <hip/hip_bf16.h>

#define N_NODES 100000
#define N_EDGES 1600000
#define IN_CH 50
#define NPB 512                                   // nodes per bucket (dst >> 9)
#define NB ((N_NODES + NPB - 1) / NPB)            // 196 buckets
#define EPB 4096                                  // edges per block, binning passes
#define NBLK_A ((N_EDGES + EPB - 1) / EPB)        // 391 blocks
#define PAD_BLOCKS ((N_NODES * 64) / 256)         // 25000

// ---- 1. coarse bucket histogram + (extra blocks) pad x -> xb bf16 ----
__global__ __launch_bounds__(256) void count_pad_kernel(const int* __restrict__ dst,
                                                        int* __restrict__ bucket_cnt,
                                                        const float* __restrict__ x,
                                                        unsigned short* __restrict__ xb) {
    __shared__ int bc[NB];
    if (blockIdx.x < NBLK_A) {
        int t = threadIdx.x;
        if (t < NB) bc[t] = 0;
        __syncthreads();
        int e0 = blockIdx.x * EPB;
        int e1 = min(e0 + EPB, N_EDGES);
        for (int i = e0 + t; i < e1; i += 256)
            atomicAdd(&bc[dst[i] >> 9], 1);
        __syncthreads();
        if (t < NB) { int v = bc[t]; if (v) atomicAdd(&bucket_cnt[t], v); }
    } else {
        int t = (blockIdx.x - NBLK_A) * 256 + threadIdx.x;   // < N_NODES*64
        int n = t >> 6, c = t & 63;
        float v = (c < IN_CH) ? x[n * IN_CH + c] : 0.0f;
        __hip_bfloat16 hb = __float2bfloat16(v);
        xb[t] = *(unsigned short*)&hb;
    }
}

// ---- 2. exclusive scan of bucket sizes ----
__global__ __launch_bounds__(256) void bucket_scan(const int* __restrict__ bucket_cnt,
                                                   int* __restrict__ bucket_base,
                                                   int* __restrict__ bucket_cursor) {
    __shared__ int s[256];
    int t = threadIdx.x;
    int v = (t < NB) ? bucket_cnt[t] : 0;
    s[t] = v;
    __syncthreads();
    for (int off = 1; off < 256; off <<= 1) {
        int tmp = (t >= off) ? s[t - off] : 0;
        __syncthreads();
        s[t] += tmp;
        __syncthreads();
    }
    if (t < NB) { int base = s[t] - v; bucket_base[t] = base; bucket_cursor[t] = base; }
}

// ---- 3. bin edges as packed u32: (dst&511)<<17 | src  (src < 2^17) ----
__global__ __launch_bounds__(256) void bucket_bin(const int* __restrict__ src,
                                                  const int* __restrict__ dst,
                                                  int* __restrict__ bucket_cursor,
                                                  unsigned* __restrict__ binned) {
    __shared__ int bc[NB];
    __shared__ int boff[NB];
    int t = threadIdx.x;
    if (t < NB) bc[t] = 0;
    __syncthreads();
    int e0 = blockIdx.x * EPB;
    int e1 = min(e0 + EPB, N_EDGES);
    for (int i = e0 + t; i < e1; i += 256)
        atomicAdd(&bc[dst[i] >> 9], 1);
    __syncthreads();
    if (t < NB) {
        int v = bc[t];
        boff[t] = v ? atomicAdd(&bucket_cursor[t], v) : 0;
        bc[t] = 0;                                 // reuse as local cursor
    }
    __syncthreads();
    for (int i = e0 + t; i < e1; i += 256) {
        int d = dst[i];
        int b = d >> 9;
        int k = atomicAdd(&bc[b], 1);
        binned[boff[b] + k] = ((unsigned)(d & 511) << 17) | (unsigned)src[i];
    }
}

// ---- 4. per-bucket fine sort (u32 payload) ----
__global__ __launch_bounds__(256) void bucket_fine(
    const unsigned* __restrict__ binned,
    const int* __restrict__ bucket_base, const int* __restrict__ bucket_cnt,
    int* __restrict__ cnt, int* __restrict__ row_start, int* __restrict__ csr_src) {
    __shared__ int lcnt[NPB];
    __shared__ int lofs[NPB];
    __shared__ int sc[256];
    int t = threadIdx.x;
    int b = blockIdx.x;
    int nbase = b * NPB;
    int ebase = bucket_base[b];
    int ecnt  = bucket_cnt[b];
    lcnt[t] = 0; lcnt[t + 256] = 0;
    __syncthreads();
    for (int i = t; i < ecnt; i += 256)
        atomicAdd(&lcnt[(binned[ebase + i] >> 17) & 511], 1);
    __syncthreads();
    int v0 = lcnt[2 * t], v1 = lcnt[2 * t + 1];
    int pair = v0 + v1;
    sc[t] = pair;
    __syncthreads();
    for (int off = 1; off < 256; off <<= 1) {
        int tmp = (t >= off) ? sc[t - off] : 0;
        __syncthreads();
        sc[t] += tmp;
        __syncthreads();
    }
    int excl = sc[t] - pair;
    lofs[2 * t] = excl;
    lofs[2 * t + 1] = excl + v0;
    __syncthreads();
    {
        int n0 = nbase + t;
        if (n0 < N_NODES) { cnt[n0] = lcnt[t]; row_start[n0] = ebase + lofs[t]; }
        int n1 = nbase + t + 256;
        if (n1 < N_NODES) { cnt[n1] = lcnt[t + 256]; row_start[n1] = ebase + lofs[t + 256]; }
    }
    __syncthreads();
    for (int i = t; i < ecnt; i += 256) {
        unsigned p = binned[ebase + i];
        int d = (int)((p >> 17) & 511);
        int k = atomicAdd(&lofs[d], 1);
        csr_src[ebase + k] = (int)(p & 0x1FFFFu);
    }
}

// unpack 8 bf16 from uint4, predicated fma into acc[0..8)
__device__ __forceinline__ void upadd8(float* a, uint4 v, float p) {
    a[0] = fmaf(p, __uint_as_float(v.x << 16), a[0]);
    a[1] = fmaf(p, __uint_as_float(v.x & 0xffff0000u), a[1]);
    a[2] = fmaf(p, __uint_as_float(v.y << 16), a[2]);
    a[3] = fmaf(p, __uint_as_float(v.y & 0xffff0000u), a[3]);
    a[4] = fmaf(p, __uint_as_float(v.z << 16), a[4]);
    a[5] = fmaf(p, __uint_as_float(v.z & 0xffff0000u), a[5]);
    a[6] = fmaf(p, __uint_as_float(v.w << 16), a[6]);
    a[7] = fmaf(p, __uint_as_float(v.w & 0xffff0000u), a[7]);
}

// wave-local LDS fence: LDS ops of one wave complete in order; no block barrier.
#define WAVE_LDS_FENCE() __asm__ volatile("s_waitcnt lgkmcnt(0)" ::: "memory")

// Gather-mean of 4 nodes (nb..nb+3) per wave, chains interleaved (proven R7 shape).
__device__ __forceinline__ void gather4(
    const unsigned short* __restrict__ featb, const int* __restrict__ csr_src,
    const int* __restrict__ row_start, const int* __restrict__ cnt,
    int nb, int lane, float acc[4][8]) {
    int g  = lane >> 3;
    int cw = (lane & 7) * 8;
    int start[4], deg[4], sv[4];
    int dmax = 0;
    #pragma unroll
    for (int i = 0; i < 4; ++i) {
        start[i] = row_start[nb + i];
        deg[i]   = cnt[nb + i];
        dmax = max(dmax, deg[i]);
        #pragma unroll
        for (int c = 0; c < 8; ++c) acc[i][c] = 0.f;
    }
    #pragma unroll
    for (int i = 0; i < 4; ++i)
        sv[i] = (lane < deg[i]) ? csr_src[start[i] + lane] : 0;

    #pragma unroll
    for (int cb = 0; cb < 64; cb += 16) {
        if (cb >= dmax) break;                 // wave-uniform
        #pragma unroll
        for (int i = 0; i < 4; ++i) {
            int rem = deg[i] - cb;
            if (rem > 0) {                     // wave-uniform
                int s0 = __shfl(sv[i], cb + g);
                int s1 = __shfl(sv[i], cb + 8 + g);
                float p0 = (g < rem) ? 1.f : 0.f;
                float p1 = (g + 8 < rem) ? 1.f : 0.f;
                uint4 v0 = *(const uint4*)(featb + s0 * 64 + cw);
                uint4 v1 = *(const uint4*)(featb + s1 * 64 + cw);
                upadd8(acc[i], v0, p0);
                upadd8(acc[i], v1, p1);
            }
        }
    }
    if (dmax > 64) {                           // rare tail
        for (int i = 0; i < 4; ++i) {
            for (int c0 = 64; c0 < deg[i]; c0 += 64) {
                int rem = deg[i] - c0; if (rem > 64) rem = 64;
                int sx = (lane < rem) ? csr_src[start[i] + c0 + lane] : 0;
                for (int cb = 0; cb < rem; cb += 16) {
                    int s0 = __shfl(sx, cb + g);
                    int s1 = __shfl(sx, cb + 8 + g);
                    float p0 = (cb + g < rem) ? 1.f : 0.f;
                    float p1 = (cb + 8 + g < rem) ? 1.f : 0.f;
                    uint4 v0 = *(const uint4*)(featb + s0 * 64 + cw);
                    uint4 v1 = *(const uint4*)(featb + s1 * 64 + cw);
                    upadd8(acc[i], v0, p0);
                    upadd8(acc[i], v1, p1);
                }
            }
        }
    }
    #pragma unroll
    for (int i = 0; i < 4; ++i) {
        float inv = 1.0f / fmaxf((float)deg[i], 1.0f);
        #pragma unroll
        for (int c = 0; c < 8; ++c) {
            float t = acc[i][c];
            t += __shfl_xor(t, 8);
            t += __shfl_xor(t, 16);
            t += __shfl_xor(t, 32);
            acc[i][c] = t * inv;
        }
    }
}

__device__ __forceinline__ float bf16u(unsigned short u) {
    return __uint_as_float(((unsigned)u) << 16);
}

// ---- 5. layer 1 fused: 4 nodes/wave; gather(xb) + self(xb) + GEMM(100x64) + ReLU -> h1b ----
__global__ __launch_bounds__(256) void layer1_fused(
    const unsigned short* __restrict__ xb,
    const int* __restrict__ csr_src, const int* __restrict__ row_start,
    const int* __restrict__ cnt, const float* __restrict__ W1,
    const float* __restrict__ b1, unsigned short* __restrict__ h1b) {
    int wv   = threadIdx.x >> 6;
    int lane = threadIdx.x & 63;
    int nb   = (blockIdx.x * 4 + wv) * 4;      // N_NODES % 16 == 0

    float acc[4][8];
    gather4(xb, csr_src, row_start, cnt, nb, lane, acc);

    __shared__ __align__(16) float selfF[4][4][64];
    __shared__ __align__(16) float meanF[4][4][64];
    #pragma unroll
    for (int i = 0; i < 4; ++i) {
        selfF[wv][i][lane] = bf16u(xb[((nb + i) << 6) + lane]);   // coalesced 128B/node
        if (lane < 8) {
            *(float4*)&meanF[wv][i][lane * 8] =
                make_float4(acc[i][0], acc[i][1], acc[i][2], acc[i][3]);
            *(float4*)&meanF[wv][i][lane * 8 + 4] =
                make_float4(acc[i][4], acc[i][5], acc[i][6], acc[i][7]);
        }
    }
    WAVE_LDS_FENCE();

    float ao[4];
    float bb = b1[lane];
    #pragma unroll
    for (int i = 0; i < 4; ++i) ao[i] = bb;
    #pragma unroll
    for (int k = 0; k < IN_CH; ++k) {
        float w = W1[k * 64 + lane];           // loaded once, reused x4
        #pragma unroll
        for (int i = 0; i < 4; ++i) ao[i] = fmaf(selfF[wv][i][k], w, ao[i]);
    }
    #pragma unroll
    for (int k = 0; k < IN_CH; ++k) {
        float w = W1[(IN_CH + k) * 64 + lane];
        #pragma unroll
        for (int i = 0; i < 4; ++i) ao[i] = fmaf(meanF[wv][i][k], w, ao[i]);
    }
    #pragma unroll
    for (int i = 0; i < 4; ++i) {
        float r = fmaxf(ao[i], 0.f);
        __hip_bfloat16 hb = __float2bfloat16(r);
        h1b[((nb + i) << 6) + lane] = *(unsigned short*)&hb;
    }
}

// ---- 6. layers 2+3 fused: 4 nodes/wave; gather(h1b) + self(h1b) + GEMM(128x32) + dot(W3) ----
__global__ __launch_bounds__(256) void layer23_fused(
    const unsigned short* __restrict__ h1b,
    const int* __restrict__ csr_src, const int* __restrict__ row_start,
    const int* __restrict__ cnt, const float* __restrict__ W2,
    const float* __restrict__ b2, const float* __restrict__ W3,
    const float* __restrict__ b3, float* __restrict__ out) {
    int wv   = threadIdx.x >> 6;
    int lane = threadIdx.x & 63;
    int nb   = (blockIdx.x * 4 + wv) * 4;

    float acc[4][8];
    gather4(h1b, csr_src, row_start, cnt, nb, lane, acc);

    __shared__ __align__(16) float featL[4][4][128];   // [0,64)=self, [64,128)=mean
    #pragma unroll
    for (int i = 0; i < 4; ++i) {
        featL[wv][i][lane] = bf16u(h1b[((nb + i) << 6) + lane]);
        if (lane < 8) {
            *(float4*)&featL[wv][i][64 + lane * 8] =
                make_float4(acc[i][0], acc[i][1], acc[i][2], acc[i][3]);
            *(float4*)&featL[wv][i][64 + lane * 8 + 4] =
                make_float4(acc[i][4], acc[i][5], acc[i][6], acc[i][7]);
        }
    }
    WAVE_LDS_FENCE();

    int hh = lane >> 5;                        // half-wave id: nodes nb+hh, nb+2+hh
    int j  = lane & 31;
    float a0 = b2[j], a1 = a0;
    #pragma unroll
    for (int k = 0; k < 128; ++k) {
        float w = W2[k * 32 + j];
        a0 = fmaf(featL[wv][hh][k],     w, a0);
        a1 = fmaf(featL[wv][2 + hh][k], w, a1);
    }
    float w3 = W3[j];
    float c3 = b3[0];
    float v0 = fmaxf(a0, 0.f) * w3;
    float v1 = fmaxf(a1, 0.f) * w3;
    #pragma unroll
    for (int off = 1; off <= 16; off <<= 1) {
        v0 += __shfl_xor(v0, off);
        v1 += __shfl_xor(v1, off);
    }
    if (j == 0) {
        out[nb + hh]     = v0 + c3;
        out[nb + 2 + hh] = v1 + c3;
    }
}

extern "C" void kernel_launch(void* const* d_in, const int* in_sizes, int n_in,
                              void* d_out, int out_size, void* d_ws, size_t ws_size,
                              hipStream_t stream) {
    const float* x   = (const float*)d_in[0];
    const int*   ei  = (const int*)d_in[1];
    const int*   src = ei;
    const int*   dst = ei + N_EDGES;
    const float* W1  = (const float*)d_in[2];
    const float* b1  = (const float*)d_in[3];
    const float* W2  = (const float*)d_in[4];
    const float* b2  = (const float*)d_in[5];
    const float* W3  = (const float*)d_in[6];
    const float* b3  = (const float*)d_in[7];
    float* out = (float*)d_out;

    // ws (~39 MB): buckets | cnt | row_start | csr_src |
    //   binned u32[E] 6.4MB | xb bf16 12.8MB | h1b bf16 12.8MB
    char* ws = (char*)d_ws;
    auto align = [](size_t v) { return (v + 255) & ~(size_t)255; };
    size_t o = 0;
    int* bucket_cnt    = (int*)(ws + o); o = align(o + 256 * 4);
    int* bucket_base   = (int*)(ws + o); o = align(o + 256 * 4);
    int* bucket_cursor = (int*)(ws + o); o = align(o + 256 * 4);
    int* cnt       = (int*)(ws + o); o = align(o + (size_t)N_NODES * 4);
    int* row_start = (int*)(ws + o); o = align(o + (size_t)N_NODES * 4);
    int* csr_src   = (int*)(ws + o); o = align(o + (size_t)N_EDGES * 4);
    unsigned* binned = (unsigned*)(ws + o); o = align(o + (size_t)N_EDGES * 4);
    unsigned short* xb  = (unsigned short*)(ws + o); o = align(o + (size_t)N_NODES * 64 * 2);
    unsigned short* h1b = (unsigned short*)(ws + o); o = align(o + (size_t)N_NODES * 64 * 2);

    hipMemsetAsync(bucket_cnt, 0, 256 * sizeof(int), stream);

    count_pad_kernel<<<NBLK_A + PAD_BLOCKS, 256, 0, stream>>>(dst, bucket_cnt, x, xb);
    bucket_scan<<<1, 256, 0, stream>>>(bucket_cnt, bucket_base, bucket_cursor);
    bucket_bin<<<NBLK_A, 256, 0, stream>>>(src, dst, bucket_cursor, binned);
    bucket_fine<<<NB, 256, 0, stream>>>(binned, bucket_base, bucket_cnt,
                                        cnt, row_start, csr_src);

    layer1_fused<<<N_NODES / 16, 256, 0, stream>>>(xb, csr_src, row_start, cnt,
                                                   W1, b1, h1b);
    layer23_fused<<<N_NODES / 16, 256, 0, stream>>>(h1b, csr_src, row_start, cnt,
                                                    W2, b2, W3, b3, out);
}